// Round 6
// baseline (438.198 us; speedup 1.0000x reference)
//
#include <hip/hip_runtime.h>
#include <hip/hip_bf16.h>
#include <stdint.h>

typedef unsigned short u16;
typedef unsigned int u32;
using f32x4  = __attribute__((ext_vector_type(4))) float;
using bf16x8 = __attribute__((ext_vector_type(8))) short;

__device__ __forceinline__ float b2f(u16 u) {
    return __uint_as_float((u32)u << 16);
}
__device__ __forceinline__ u16 f2b(float f) {
    __hip_bfloat16 h = __float2bfloat16(f);
    return *reinterpret_cast<u16*>(&h);
}
__device__ __forceinline__ short f2bs(float f) {
    return (short)f2b(f);
}
__device__ __forceinline__ int padd8(int d) { return (d + 7) & ~7; }

// ---------------------------------------------------------------------------
// Bucketed CSR build. Bucket = 512 consecutive dst nodes (dst>>9).
#define BSH 9
#define BNODES (1 << BSH)
#define BCAP 16384          // stage capacity per bucket (mean 8.2k)

// partition edges into buckets; stage entry = (src<<9) | (dst&511)
__global__ __launch_bounds__(256) void k_part(
        const int* __restrict__ src, const int* __restrict__ dst, int E,
        int* __restrict__ gCnt, u32* __restrict__ stage) {
    __shared__ int hist[128];
    __shared__ int runBase[128];
    const int tid = threadIdx.x;
    if (tid < 128) hist[tid] = 0;
    __syncthreads();
    const int base = blockIdx.x * 1024 + tid * 4;
    int s[4], d[4], bk[4], rk[4];
    bool ok[4];
    if (base + 3 < E) {
        int4 sv = *reinterpret_cast<const int4*>(src + base);
        int4 dv = *reinterpret_cast<const int4*>(dst + base);
        s[0]=sv.x; s[1]=sv.y; s[2]=sv.z; s[3]=sv.w;
        d[0]=dv.x; d[1]=dv.y; d[2]=dv.z; d[3]=dv.w;
        ok[0]=ok[1]=ok[2]=ok[3]=true;
    } else {
        #pragma unroll
        for (int j = 0; j < 4; ++j) {
            ok[j] = (base + j) < E;
            s[j] = ok[j] ? src[base + j] : 0;
            d[j] = ok[j] ? dst[base + j] : 0;
        }
    }
    #pragma unroll
    for (int j = 0; j < 4; ++j)
        if (ok[j]) { bk[j] = d[j] >> BSH; rk[j] = atomicAdd(&hist[bk[j]], 1); }
    __syncthreads();
    if (tid < 128) {
        int c = hist[tid];
        runBase[tid] = c ? atomicAdd(&gCnt[tid], c) : 0;
    }
    __syncthreads();
    #pragma unroll
    for (int j = 0; j < 4; ++j)
        if (ok[j])
            stage[(size_t)bk[j] * BCAP + runBase[bk[j]] + rk[j]] =
                ((u32)s[j] << BSH) | (u32)(d[j] & (BNODES - 1));
}

// per bucket: histogram -> dis (deg^-0.5) + padded-size total
__global__ __launch_bounds__(256) void k_b1(
        const u32* __restrict__ stage, const int* __restrict__ gCnt,
        float* __restrict__ dis, int* __restrict__ bucketPad, int N) {
    __shared__ int hist[BNODES];
    __shared__ int sW[4];
    const int b = blockIdx.x, tid = threadIdx.x;
    for (int i = tid; i < BNODES; i += 256) hist[i] = 0;
    __syncthreads();
    const int cnt = gCnt[b];
    const u32* st = stage + (size_t)b * BCAP;
    for (int e = tid; e < cnt; e += 256)
        atomicAdd(&hist[st[e] & (BNODES - 1)], 1);
    __syncthreads();
    const int nbase = b << BSH;
    int ps = 0;
    for (int i = tid; i < BNODES; i += 256) {
        int node = nbase + i;
        if (node < N) {
            int dg = hist[i];
            dis[node] = dg > 0 ? (1.0f / sqrtf((float)dg)) : 0.0f;
            ps += padd8(dg);
        }
    }
    #pragma unroll
    for (int off = 32; off; off >>= 1) ps += __shfl_down(ps, off, 64);
    int lane = tid & 63, wv = tid >> 6;
    if (lane == 0) sW[wv] = ps;
    __syncthreads();
    if (tid == 0) bucketPad[b] = sW[0] + sW[1] + sW[2] + sW[3];
}

// per bucket: re-histogram + scan -> rowst/rowend + pad + csr fill (LDS atomics)
// csr payload: (src<<7 byte-offset into 128B-row planes, weight)
__global__ __launch_bounds__(256) void k_b2(
        const u32* __restrict__ stage, const int* __restrict__ gCnt,
        const int* __restrict__ bucketPad, const float* __restrict__ dis,
        int* __restrict__ rowst, int* __restrict__ rowend,
        int2* __restrict__ csr, int N) {
    __shared__ int hist[BNODES];
    __shared__ int lofs[BNODES];
    __shared__ int cur[BNODES];
    __shared__ int sW[4];
    const int b = blockIdx.x, tid = threadIdx.x;
    for (int i = tid; i < BNODES; i += 256) hist[i] = 0;
    __syncthreads();
    const int cnt = gCnt[b];
    const u32* st = stage + (size_t)b * BCAP;
    for (int e = tid; e < cnt; e += 256)
        atomicAdd(&hist[st[e] & (BNODES - 1)], 1);
    __syncthreads();
    const int i0 = tid * 2, i1 = tid * 2 + 1;
    const int p0 = padd8(hist[i0]), p1 = padd8(hist[i1]);
    const int sps = p0 + p1;
    int x = sps;
    #pragma unroll
    for (int off = 1; off < 64; off <<= 1) {
        int y = __shfl_up(x, off, 64);
        if ((tid & 63) >= off) x += y;
    }
    int lane = tid & 63, wv = tid >> 6;
    if (lane == 63) sW[wv] = x;
    __syncthreads();
    if (tid == 0) {
        int run = 0;
        #pragma unroll
        for (int w = 0; w < 4; ++w) { int t = sW[w]; sW[w] = run; run += t; }
    }
    __syncthreads();
    const int excl = sW[wv] + (x - sps);
    lofs[i0] = excl;
    lofs[i1] = excl + p0;
    int boff = 0;
    for (int bb = 0; bb < b; ++bb) boff += bucketPad[bb];
    __syncthreads();
    const int nbase = b << BSH;
    for (int i = tid; i < BNODES; i += 256) {
        cur[i] = lofs[i];
        int node = nbase + i;
        if (node < N) {
            int dg = hist[i];
            int rsG = boff + lofs[i];
            rowst[node] = rsG;
            rowend[node] = rsG + padd8(dg);
            for (int e = dg; e < padd8(dg); ++e)
                csr[rsG + e] = make_int2(0, 0);
        }
    }
    __syncthreads();
    for (int e = tid; e < cnt; e += 256) {
        u32 sd = st[e];
        int ld = sd & (BNODES - 1);
        int s = (int)(sd >> BSH);
        int lpos = atomicAdd(&cur[ld], 1);
        float w = dis[s] * dis[nbase + ld];
        csr[boff + lpos] = make_int2(s << 7, __float_as_int(w));
    }
}

// ---------------------------------------------------------------------------
// pack both weight tensors into MFMA B-fragment order
__global__ void k_packBoth(const float* __restrict__ w1, const float* __restrict__ w2,
                           u16* __restrict__ Bp1, u16* __restrict__ Bp2) {
    int t = blockIdx.x * blockDim.x + threadIdx.x;
    const float* W; u16* Bp; int log2cw; int tt;
    if (t < 8192)        { W = w1; Bp = Bp1; log2cw = 7; tt = t; }
    else if (t < 10240)  { W = w2; Bp = Bp2; log2cw = 5; tt = t - 8192; }
    else return;
    int lane = tt & 63;
    int f = tt >> 6;
    int ks = f & 3, nblock = f >> 2;
    int col = nblock * 16 + (lane & 15);
    int cw = 1 << log2cw;
    int kterm = col >> log2cw, c = col & (cw - 1);
    int kbase = ks * 32 + (lane >> 4) * 8;
    u16 out[8];
    #pragma unroll
    for (int i = 0; i < 8; ++i)
        out[i] = f2b(W[((size_t)kterm * 128 + (kbase + i)) * cw + c]);
    *reinterpret_cast<uint4*>(Bp + (size_t)tt * 8) = *reinterpret_cast<uint4*>(out);
}

// ---------------------------------------------------------------------------
// MFMA GEMM. A_MODE: 0 = bf16 dense [Mp][128]; 1 = fp32 dense [Mp][128];
// 2 = bf16 two 64-wide planes (plane stride PSA elements).
// Output: planes of width (1<<lw), plane stride PSO elements, cb blocks at
// Out + cb*outStride.
template<int A_MODE>
__global__ __launch_bounds__(256) void k_gemm(
        const void* __restrict__ Av, size_t PSA,
        const u16* __restrict__ Bp,
        u16* __restrict__ Out, size_t outStride, size_t PSO, int lw,
        int ncb, int Mvalid) {
    const int lane = threadIdx.x & 63;
    const int wv = threadIdx.x >> 6;
    const int rowBase = blockIdx.x * 128 + wv * 32;
    const int li = lane & 15, lh = lane >> 4;

    bf16x8 a[2][4];
    #pragma unroll
    for (int rg = 0; rg < 2; ++rg) {
        int r = rowBase + rg * 16 + li;
        bool ok = (r < Mvalid);
        #pragma unroll
        for (int ks = 0; ks < 4; ++ks) {
            int feat = ks * 32 + lh * 8;
            bf16x8 v = {0,0,0,0,0,0,0,0};
            if (ok) {
                if (A_MODE == 1) {
                    const float* A = (const float*)Av;
                    const float* p = A + (size_t)r * 128 + feat;
                    float4 f0 = *reinterpret_cast<const float4*>(p);
                    float4 f1 = *reinterpret_cast<const float4*>(p + 4);
                    v[0] = f2bs(f0.x); v[1] = f2bs(f0.y);
                    v[2] = f2bs(f0.z); v[3] = f2bs(f0.w);
                    v[4] = f2bs(f1.x); v[5] = f2bs(f1.y);
                    v[6] = f2bs(f1.z); v[7] = f2bs(f1.w);
                } else if (A_MODE == 0) {
                    const u16* A = (const u16*)Av;
                    v = *reinterpret_cast<const bf16x8*>(A + (size_t)r * 128 + feat);
                } else {
                    const u16* A = (const u16*)Av;
                    v = *reinterpret_cast<const bf16x8*>(
                        A + (size_t)(feat >> 6) * PSA + (size_t)r * 64 + (feat & 63));
                }
            }
            a[rg][ks] = v;
        }
    }

    for (int cb = 0; cb < ncb; ++cb) {
        f32x4 acc[2][8];
        #pragma unroll
        for (int i = 0; i < 2; ++i)
            #pragma unroll
            for (int j = 0; j < 8; ++j)
                acc[i][j] = (f32x4){0.f, 0.f, 0.f, 0.f};
        #pragma unroll
        for (int ks = 0; ks < 4; ++ks) {
            #pragma unroll
            for (int nf = 0; nf < 8; ++nf) {
                const u16* pb = Bp + ((size_t)((cb * 8 + nf) * 4 + ks) * 64 + lane) * 8;
                bf16x8 bfr = *reinterpret_cast<const bf16x8*>(pb);
                acc[0][nf] = __builtin_amdgcn_mfma_f32_16x16x32_bf16(a[0][ks], bfr, acc[0][nf], 0, 0, 0);
                acc[1][nf] = __builtin_amdgcn_mfma_f32_16x16x32_bf16(a[1][ks], bfr, acc[1][nf], 0, 0, 0);
            }
        }
        // D layout: col = lane&15, row = (lane>>4)*4 + reg   [m89]
        u16* Ob = Out + (size_t)cb * outStride;
        #pragma unroll
        for (int rg = 0; rg < 2; ++rg) {
            #pragma unroll
            for (int nf = 0; nf < 8; ++nf) {
                int col = nf * 16 + li;
                int pl = col >> lw, cwi = col & ((1 << lw) - 1);
                #pragma unroll
                for (int r = 0; r < 4; ++r) {
                    int row = rowBase + rg * 16 + lh * 4 + r;
                    if (row < Mvalid)
                        Ob[(size_t)pl * PSO + ((size_t)row << lw) + cwi] = f2b(acc[rg][nf][r]);
                }
            }
        }
    }
}

// ---------------------------------------------------------------------------
// plane propagation: wave per (node, plane); plane = blockIdx&1 so (with
// round-robin block->XCD mapping) each XCD gathers from only ONE 6.4MB plane.
// 128B rows, lane = 1 feature. out = A*X + Add (+bias) (relu), bf16 NT out.
__global__ __launch_bounds__(256) void k_prop_w(
        const u16* __restrict__ X, const u16* __restrict__ Add,
        const float* __restrict__ bias, int relu,
        const int2* __restrict__ csr, const int* __restrict__ rs,
        const int* __restrict__ re,
        u16* __restrict__ Out, size_t PS, int n) {
    const int plane = blockIdx.x & 1;
    const int node = (int)(blockIdx.x >> 1) * 4 + (threadIdx.x >> 6);
    const int lane = threadIdx.x & 63;
    if (node >= n) return;
    const char* Xb = (const char*)(X + plane * PS) + lane * 2;
    int beg = rs[node], end = re[node];
    float ax = 0.f, bx = 0.f;
    for (int e = beg; e < end; e += 8) {
        int2 c[8];
        #pragma unroll
        for (int j = 0; j < 8; ++j) c[j] = csr[e + j];
        u16 v[8];
        #pragma unroll
        for (int j = 0; j < 8; ++j)
            v[j] = *reinterpret_cast<const u16*>(Xb + (size_t)(u32)c[j].x);
        #pragma unroll
        for (int j = 0; j < 8; ++j) {
            float w = __int_as_float(c[j].y);
            if (j & 1) bx += w * b2f(v[j]);
            else       ax += w * b2f(v[j]);
        }
    }
    ax += bx;
    size_t idx = (size_t)plane * PS + (size_t)node * 64 + lane;
    if (Add) ax += b2f(__builtin_nontemporal_load(Add + idx));
    if (bias) ax += bias[plane * 64 + lane];
    if (relu) ax = fmaxf(ax, 0.f);
    __builtin_nontemporal_store(f2b(ax), Out + idx);
}

// 32-wide propagation over 64B-row slices (3.2MB, L2-resident per XCD).
// csr offset>>1 = src*64B. 32 threads per node.
__global__ __launch_bounds__(256) void k_prop_q(
        const u16* __restrict__ X, const u16* __restrict__ Add,
        const float* __restrict__ bias,
        const int2* __restrict__ csr, const int* __restrict__ rs,
        const int* __restrict__ re,
        u16* __restrict__ OutB, float* __restrict__ OutF, int n) {
    int t = blockIdx.x * blockDim.x + threadIdx.x;
    int node = t >> 5, j = t & 31;
    if (node >= n) return;
    const char* Xb = (const char*)X + j * 2;
    float acc = 0.f, acc2 = 0.f;
    int beg = rs[node], end = re[node];
    for (int e = beg; e < end; e += 8) {
        int2 c[8];
        #pragma unroll
        for (int q = 0; q < 8; ++q) c[q] = csr[e + q];
        float v[8];
        #pragma unroll
        for (int q = 0; q < 8; ++q)
            v[q] = b2f(*reinterpret_cast<const u16*>(Xb + ((size_t)(u32)c[q].x >> 1)));
        #pragma unroll
        for (int q = 0; q < 8; ++q) {
            if (q & 1) acc2 += __int_as_float(c[q].y) * v[q];
            else       acc  += __int_as_float(c[q].y) * v[q];
        }
    }
    acc += acc2;
    if (Add) acc += b2f(__builtin_nontemporal_load(Add + (size_t)node * 32 + j));
    if (bias) acc += bias[j];
    if (OutF) __builtin_nontemporal_store(acc, OutF + (size_t)node * 32 + j);
    else      __builtin_nontemporal_store(f2b(acc), OutB + (size_t)node * 32 + j);
}

// ---------------------------------------------------------------------------
static inline char* alignup(char* p, size_t a) {
    return (char*)(((uintptr_t)p + a - 1) & ~(uintptr_t)(a - 1));
}

extern "C" void kernel_launch(void* const* d_in, const int* in_sizes, int n_in,
                              void* d_out, int out_size, void* d_ws, size_t ws_size,
                              hipStream_t stream) {
    const float* x  = (const float*)d_in[0];
    const int*   ei = (const int*)d_in[1];
    const float* w1 = (const float*)d_in[2];
    const float* b1 = (const float*)d_in[3];
    const float* w2 = (const float*)d_in[4];
    const float* b2 = (const float*)d_in[5];

    const int N = in_sizes[0] / 128;
    const int E = in_sizes[1] / 2;
    const int Mp = ((N + 127) / 128) * 128;
    const int NBK = (N + BNODES - 1) >> BSH;
    const int* srcIdx = ei;
    const int* dstIdx = ei + E;

    // workspace carve (256B aligned pieces)
    char* p = (char*)d_ws;
    int* rowst  = (int*)p;                 p = alignup(p + (size_t)N * 4, 256);
    int* rowend = (int*)p;                 p = alignup(p + (size_t)N * 4, 256);
    float* dis  = (float*)p;               p = alignup(p + (size_t)N * 4, 256);
    int* gCnt   = (int*)p;                 p = alignup(p + 128 * 4, 256);
    int* bucketPad = (int*)p;              p = alignup(p + 128 * 4, 256);
    int2* csr   = (int2*)p;                p = alignup(p + ((size_t)E + 8 * (size_t)N) * 8, 256);
    u16* Bp1    = (u16*)p;                 p = alignup(p + (size_t)128 * 512 * 2, 256);
    u16* Bp2    = (u16*)p;                 p = alignup(p + (size_t)128 * 128 * 2, 256);
    u16* G      = (u16*)p;                 p = alignup(p + (size_t)Mp * 512 * 2, 256);
    const size_t GS  = (size_t)Mp * 128;   // per-G-buffer stride (2 planes inside)
    const size_t PS1 = (size_t)Mp * 64;    // 128B-row plane stride
    const size_t SSq = (size_t)Mp * 32;    // 64B-row slice stride
    // t2 region doubles as the partition stage buffer (dead until prop#1)
    size_t t2Bytes = GS * 2, stageBytes = (size_t)NBK * BCAP * 4;
    size_t u = t2Bytes > stageBytes ? t2Bytes : stageBytes;
    u16* t2     = (u16*)p;
    u32* stage  = (u32*)p;                 p = alignup(p + u, 256);
    u16* t1     = (u16*)p;                 p = alignup(p + GS * 2, 256);
    u16* h      = (u16*)p;                 p = alignup(p + GS * 2, 256);
    u16* Gc = G;
    u16* s1 = t2;
    u16* s2 = t1;

    hipMemsetAsync(gCnt, 0, 128 * sizeof(int), stream);

    // ---- CSR build (bucketed counting sort; single-XCD-owned csr writes)
    k_part<<<(E + 1023) / 1024, 256, 0, stream>>>(srcIdx, dstIdx, E, gCnt, stage);
    k_b1  <<<NBK, 256, 0, stream>>>(stage, gCnt, dis, bucketPad, N);
    k_b2  <<<NBK, 256, 0, stream>>>(stage, gCnt, bucketPad, dis, rowst, rowend, csr, N);
    k_packBoth<<<(10240 + 255) / 256, 256, 0, stream>>>(w1, w2, Bp1, Bp2);

    const int gb = Mp / 128;
    const int pwBlocks = ((N + 3) / 4) * 2;
    const int pqBlocks = (N * 32 + 255) / 256;

    // ---- layer 1: Gk = x @ W1_k (4 buffers, each 2x64-wide planes)
    k_gemm<1><<<gb, 256, 0, stream>>>(x, 0, Bp1, G, GS, PS1, 6, 4, N);
    // Horner: t2 = A*G3 + G2 ; t1 = A*t2 + G1 ; h = relu(A*t1 + G0 + b1)
    k_prop_w<<<pwBlocks, 256, 0, stream>>>(G + 3 * GS, G + 2 * GS, nullptr, 0,
                                           csr, rowst, rowend, t2, PS1, N);
    k_prop_w<<<pwBlocks, 256, 0, stream>>>(t2, G + 1 * GS, nullptr, 0,
                                           csr, rowst, rowend, t1, PS1, N);
    k_prop_w<<<pwBlocks, 256, 0, stream>>>(t1, G + 0 * GS, b1, 1,
                                           csr, rowst, rowend, h, PS1, N);

    // ---- layer 2: Gc = h @ [V0..V3] as 4 32-wide slices, then 32-wide Horner
    k_gemm<2><<<gb, 256, 0, stream>>>(h, PS1, Bp2, Gc, GS, SSq, 5, 1, N);
    k_prop_q<<<pqBlocks, 256, 0, stream>>>(Gc + 3 * SSq, Gc + 2 * SSq, nullptr,
                                           csr, rowst, rowend, s1, nullptr, N);
    k_prop_q<<<pqBlocks, 256, 0, stream>>>(s1, Gc + 1 * SSq, nullptr,
                                           csr, rowst, rowend, s2, nullptr, N);
    k_prop_q<<<pqBlocks, 256, 0, stream>>>(s2, Gc, b2,
                                           csr, rowst, rowend, nullptr, (float*)d_out, N);
}

// Round 7
// 386.361 us; speedup vs baseline: 1.1342x; 1.1342x over previous
//
#include <hip/hip_runtime.h>
#include <hip/hip_bf16.h>
#include <stdint.h>

typedef unsigned short u16;
typedef unsigned int u32;
typedef unsigned long long u64;
using f32x4  = __attribute__((ext_vector_type(4))) float;
using bf16x8 = __attribute__((ext_vector_type(8))) short;

__device__ __forceinline__ float b2f(u16 u) {
    return __uint_as_float((u32)u << 16);
}
__device__ __forceinline__ u16 f2b(float f) {
    __hip_bfloat16 h = __float2bfloat16(f);
    return *reinterpret_cast<u16*>(&h);
}
__device__ __forceinline__ short f2bs(float f) {
    return (short)f2b(f);
}
__device__ __forceinline__ int padd8(int d) { return (d + 7) & ~7; }

// ---------------------------------------------------------------------------
// Bucketed CSR build. Bucket = 512 consecutive dst nodes (dst>>9).
#define BSH 9
#define BNODES (1 << BSH)
#define BCAP 16384          // stage capacity per bucket (mean 8.2k)

// partition edges into buckets; stage entry = (src<<9) | (dst&511)
__global__ __launch_bounds__(256) void k_part(
        const int* __restrict__ src, const int* __restrict__ dst, int E,
        int* __restrict__ gCnt, u32* __restrict__ stage) {
    __shared__ int hist[128];
    __shared__ int runBase[128];
    const int tid = threadIdx.x;
    if (tid < 128) hist[tid] = 0;
    __syncthreads();
    const int base = blockIdx.x * 1024 + tid * 4;
    int s[4], d[4], bk[4], rk[4];
    bool ok[4];
    if (base + 3 < E) {
        int4 sv = *reinterpret_cast<const int4*>(src + base);
        int4 dv = *reinterpret_cast<const int4*>(dst + base);
        s[0]=sv.x; s[1]=sv.y; s[2]=sv.z; s[3]=sv.w;
        d[0]=dv.x; d[1]=dv.y; d[2]=dv.z; d[3]=dv.w;
        ok[0]=ok[1]=ok[2]=ok[3]=true;
    } else {
        #pragma unroll
        for (int j = 0; j < 4; ++j) {
            ok[j] = (base + j) < E;
            s[j] = ok[j] ? src[base + j] : 0;
            d[j] = ok[j] ? dst[base + j] : 0;
        }
    }
    #pragma unroll
    for (int j = 0; j < 4; ++j)
        if (ok[j]) { bk[j] = d[j] >> BSH; rk[j] = atomicAdd(&hist[bk[j]], 1); }
    __syncthreads();
    if (tid < 128) {
        int c = hist[tid];
        runBase[tid] = c ? atomicAdd(&gCnt[tid], c) : 0;
    }
    __syncthreads();
    #pragma unroll
    for (int j = 0; j < 4; ++j)
        if (ok[j])
            stage[(size_t)bk[j] * BCAP + runBase[bk[j]] + rk[j]] =
                ((u32)s[j] << BSH) | (u32)(d[j] & (BNODES - 1));
}

// per bucket: histogram -> dis (deg^-0.5) + padded-size total
__global__ __launch_bounds__(256) void k_b1(
        const u32* __restrict__ stage, const int* __restrict__ gCnt,
        float* __restrict__ dis, int* __restrict__ bucketPad, int N) {
    __shared__ int hist[BNODES];
    __shared__ int sW[4];
    const int b = blockIdx.x, tid = threadIdx.x;
    for (int i = tid; i < BNODES; i += 256) hist[i] = 0;
    __syncthreads();
    const int cnt = gCnt[b];
    const u32* st = stage + (size_t)b * BCAP;
    for (int e = tid; e < cnt; e += 256)
        atomicAdd(&hist[st[e] & (BNODES - 1)], 1);
    __syncthreads();
    const int nbase = b << BSH;
    int ps = 0;
    for (int i = tid; i < BNODES; i += 256) {
        int node = nbase + i;
        if (node < N) {
            int dg = hist[i];
            dis[node] = dg > 0 ? (1.0f / sqrtf((float)dg)) : 0.0f;
            ps += padd8(dg);
        }
    }
    #pragma unroll
    for (int off = 32; off; off >>= 1) ps += __shfl_down(ps, off, 64);
    int lane = tid & 63, wv = tid >> 6;
    if (lane == 0) sW[wv] = ps;
    __syncthreads();
    if (tid == 0) bucketPad[b] = sW[0] + sW[1] + sW[2] + sW[3];
}

// per bucket: re-histogram + scan -> rowst/rowend + pad + csr fill (LDS atomics)
// csr payload: (src<<8 byte-offset for 256B dense rows, weight)
__global__ __launch_bounds__(256) void k_b2(
        const u32* __restrict__ stage, const int* __restrict__ gCnt,
        const int* __restrict__ bucketPad, const float* __restrict__ dis,
        int* __restrict__ rowst, int* __restrict__ rowend,
        int2* __restrict__ csr, int N) {
    __shared__ int hist[BNODES];
    __shared__ int lofs[BNODES];
    __shared__ int cur[BNODES];
    __shared__ int sW[4];
    const int b = blockIdx.x, tid = threadIdx.x;
    for (int i = tid; i < BNODES; i += 256) hist[i] = 0;
    __syncthreads();
    const int cnt = gCnt[b];
    const u32* st = stage + (size_t)b * BCAP;
    for (int e = tid; e < cnt; e += 256)
        atomicAdd(&hist[st[e] & (BNODES - 1)], 1);
    __syncthreads();
    const int i0 = tid * 2, i1 = tid * 2 + 1;
    const int p0 = padd8(hist[i0]), p1 = padd8(hist[i1]);
    const int sps = p0 + p1;
    int x = sps;
    #pragma unroll
    for (int off = 1; off < 64; off <<= 1) {
        int y = __shfl_up(x, off, 64);
        if ((tid & 63) >= off) x += y;
    }
    int lane = tid & 63, wv = tid >> 6;
    if (lane == 63) sW[wv] = x;
    __syncthreads();
    if (tid == 0) {
        int run = 0;
        #pragma unroll
        for (int w = 0; w < 4; ++w) { int t = sW[w]; sW[w] = run; run += t; }
    }
    __syncthreads();
    const int excl = sW[wv] + (x - sps);
    lofs[i0] = excl;
    lofs[i1] = excl + p0;
    int boff = 0;
    for (int bb = 0; bb < b; ++bb) boff += bucketPad[bb];
    __syncthreads();
    const int nbase = b << BSH;
    for (int i = tid; i < BNODES; i += 256) {
        cur[i] = lofs[i];
        int node = nbase + i;
        if (node < N) {
            int dg = hist[i];
            int rsG = boff + lofs[i];
            rowst[node] = rsG;
            rowend[node] = rsG + padd8(dg);
            for (int e = dg; e < padd8(dg); ++e)
                csr[rsG + e] = make_int2(0, 0);
        }
    }
    __syncthreads();
    for (int e = tid; e < cnt; e += 256) {
        u32 sd = st[e];
        int ld = sd & (BNODES - 1);
        int s = (int)(sd >> BSH);
        int lpos = atomicAdd(&cur[ld], 1);
        float w = dis[s] * dis[nbase + ld];
        csr[boff + lpos] = make_int2(s << 8, __float_as_int(w));
    }
}

// ---------------------------------------------------------------------------
// pack both weight tensors into MFMA "A-operand" (W) fragment order:
// frag f = nblock*4 + ks; lane l holds W[ks*32 + (l>>4)*8 + i][nblock*16 + (l&15)]
__global__ void k_packBoth(const float* __restrict__ w1, const float* __restrict__ w2,
                           u16* __restrict__ Bp1, u16* __restrict__ Bp2) {
    int t = blockIdx.x * blockDim.x + threadIdx.x;
    const float* W; u16* Bp; int log2cw; int tt;
    if (t < 8192)        { W = w1; Bp = Bp1; log2cw = 7; tt = t; }
    else if (t < 10240)  { W = w2; Bp = Bp2; log2cw = 5; tt = t - 8192; }
    else return;
    int lane = tt & 63;
    int f = tt >> 6;
    int ks = f & 3, nblock = f >> 2;
    int col = nblock * 16 + (lane & 15);
    int cw = 1 << log2cw;
    int kterm = col >> log2cw, c = col & (cw - 1);
    int kbase = ks * 32 + (lane >> 4) * 8;
    u16 out[8];
    #pragma unroll
    for (int i = 0; i < 8; ++i)
        out[i] = f2b(W[((size_t)kterm * 128 + (kbase + i)) * cw + c]);
    *reinterpret_cast<uint4*>(Bp + (size_t)tt * 8) = *reinterpret_cast<uint4*>(out);
}

// ---------------------------------------------------------------------------
// MFMA GEMM, operand-swapped: acc = mfma(W_frag [A-op], X_frag [B-op], acc)
// => D row = output feature (lh*4+reg), D col = node (li):
// each lane packs 4 consecutive features of one node into ONE 8B store.
// A kept in registers across ncb column-blocks of 128. Dense out [row][128].
template<int A_FP32>
__global__ __launch_bounds__(256) void k_gemm(
        const void* __restrict__ Av, const u16* __restrict__ Bp,
        u16* __restrict__ Out, size_t outStride, int ncb, int Mvalid) {
    const int lane = threadIdx.x & 63;
    const int wv = threadIdx.x >> 6;
    const int rowBase = blockIdx.x * 128 + wv * 32;
    const int li = lane & 15, lh = lane >> 4;

    bf16x8 a[2][4];
    #pragma unroll
    for (int rg = 0; rg < 2; ++rg) {
        int r = rowBase + rg * 16 + li;
        bool ok = (r < Mvalid);
        #pragma unroll
        for (int ks = 0; ks < 4; ++ks) {
            int feat = ks * 32 + lh * 8;
            bf16x8 v = {0,0,0,0,0,0,0,0};
            if (ok) {
                if (A_FP32) {
                    const float* A = (const float*)Av;
                    const float* p = A + (size_t)r * 128 + feat;
                    float4 f0 = *reinterpret_cast<const float4*>(p);
                    float4 f1 = *reinterpret_cast<const float4*>(p + 4);
                    v[0] = f2bs(f0.x); v[1] = f2bs(f0.y);
                    v[2] = f2bs(f0.z); v[3] = f2bs(f0.w);
                    v[4] = f2bs(f1.x); v[5] = f2bs(f1.y);
                    v[6] = f2bs(f1.z); v[7] = f2bs(f1.w);
                } else {
                    const u16* A = (const u16*)Av;
                    v = *reinterpret_cast<const bf16x8*>(A + (size_t)r * 128 + feat);
                }
            }
            a[rg][ks] = v;
        }
    }

    for (int cb = 0; cb < ncb; ++cb) {
        f32x4 acc[2][8];
        #pragma unroll
        for (int i = 0; i < 2; ++i)
            #pragma unroll
            for (int j = 0; j < 8; ++j)
                acc[i][j] = (f32x4){0.f, 0.f, 0.f, 0.f};
        #pragma unroll
        for (int ks = 0; ks < 4; ++ks) {
            #pragma unroll
            for (int nf = 0; nf < 8; ++nf) {
                const u16* pb = Bp + ((size_t)((cb * 8 + nf) * 4 + ks) * 64 + lane) * 8;
                bf16x8 wfr = *reinterpret_cast<const bf16x8*>(pb);
                // swapped: W as A-operand, X as B-operand
                acc[0][nf] = __builtin_amdgcn_mfma_f32_16x16x32_bf16(wfr, a[0][ks], acc[0][nf], 0, 0, 0);
                acc[1][nf] = __builtin_amdgcn_mfma_f32_16x16x32_bf16(wfr, a[1][ks], acc[1][nf], 0, 0, 0);
            }
        }
        // D: row = feature-in-16 = lh*4+r, col = node-in-16 = li  [m89]
        u16* Ob = Out + (size_t)cb * outStride;
        #pragma unroll
        for (int rg = 0; rg < 2; ++rg) {
            int node = rowBase + rg * 16 + li;
            if (node < Mvalid) {
                #pragma unroll
                for (int nf = 0; nf < 8; ++nf) {
                    u64 pk = (u64)f2b(acc[rg][nf][0])
                           | ((u64)f2b(acc[rg][nf][1]) << 16)
                           | ((u64)f2b(acc[rg][nf][2]) << 32)
                           | ((u64)f2b(acc[rg][nf][3]) << 48);
                    *reinterpret_cast<u64*>(&Ob[(size_t)node * 128 + nf * 16 + lh * 4]) = pk;
                }
            }
        }
    }
}

// ---------------------------------------------------------------------------
// plane propagation over DENSE 256B rows: wave per (node, plane);
// plane = blockIdx&1 -> with round-robin block->XCD mapping, each XCD only
// touches its plane's 64B lines (disjoint line sets, ~6.4MB footprint).
// lane = 1 feature (u16 gather). out = A*X + Add (+bias) (relu), bf16 NT out.
__global__ __launch_bounds__(256) void k_prop_w(
        const u16* __restrict__ X, const u16* __restrict__ Add,
        const float* __restrict__ bias, int relu,
        const int2* __restrict__ csr, const int* __restrict__ rs,
        const int* __restrict__ re,
        u16* __restrict__ Out, int n) {
    const int plane = blockIdx.x & 1;
    const int node = (int)(blockIdx.x >> 1) * 4 + (threadIdx.x >> 6);
    const int lane = threadIdx.x & 63;
    if (node >= n) return;
    const char* Xb = (const char*)X + plane * 128 + lane * 2;
    int beg = rs[node], end = re[node];
    float ax = 0.f, bx = 0.f;
    for (int e = beg; e < end; e += 8) {
        int2 c[8];
        #pragma unroll
        for (int j = 0; j < 8; ++j) c[j] = csr[e + j];
        u16 v[8];
        #pragma unroll
        for (int j = 0; j < 8; ++j)
            v[j] = *reinterpret_cast<const u16*>(Xb + (size_t)(u32)c[j].x);
        #pragma unroll
        for (int j = 0; j < 8; ++j) {
            float w = __int_as_float(c[j].y);
            if (j & 1) bx += w * b2f(v[j]);
            else       ax += w * b2f(v[j]);
        }
    }
    ax += bx;
    size_t idx = (size_t)node * 128 + plane * 64 + lane;
    if (Add) ax += b2f(__builtin_nontemporal_load(Add + idx));
    if (bias) ax += bias[plane * 64 + lane];
    if (relu) ax = fmaxf(ax, 0.f);
    __builtin_nontemporal_store(f2b(ax), Out + idx);
}

// 32-wide propagation: 32 threads per node; X row byte-offset = csr>>rsh,
// slice base xoffB bytes. Add is a Gc slice (dense stride 128). Padded rows.
__global__ __launch_bounds__(256) void k_prop_q(
        const u16* __restrict__ X, int xoffB, int rsh,
        const u16* __restrict__ Add,
        const float* __restrict__ bias,
        const int2* __restrict__ csr, const int* __restrict__ rs,
        const int* __restrict__ re,
        u16* __restrict__ OutB, float* __restrict__ OutF, int n) {
    int t = blockIdx.x * blockDim.x + threadIdx.x;
    int node = t >> 5, j = t & 31;
    if (node >= n) return;
    const char* Xb = (const char*)X + xoffB + j * 2;
    float acc = 0.f, acc2 = 0.f;
    int beg = rs[node], end = re[node];
    for (int e = beg; e < end; e += 8) {
        int2 c[8];
        #pragma unroll
        for (int q = 0; q < 8; ++q) c[q] = csr[e + q];
        float v[8];
        #pragma unroll
        for (int q = 0; q < 8; ++q)
            v[q] = b2f(*reinterpret_cast<const u16*>(Xb + ((size_t)(u32)c[q].x >> rsh)));
        #pragma unroll
        for (int q = 0; q < 8; ++q) {
            if (q & 1) acc2 += __int_as_float(c[q].y) * v[q];
            else       acc  += __int_as_float(c[q].y) * v[q];
        }
    }
    acc += acc2;
    if (Add) acc += b2f(__builtin_nontemporal_load(Add + (size_t)node * 128 + j));
    if (bias) acc += bias[j];
    if (OutF) __builtin_nontemporal_store(acc, OutF + (size_t)node * 32 + j);
    else      __builtin_nontemporal_store(f2b(acc), OutB + (size_t)node * 32 + j);
}

// ---------------------------------------------------------------------------
static inline char* alignup(char* p, size_t a) {
    return (char*)(((uintptr_t)p + a - 1) & ~(uintptr_t)(a - 1));
}

extern "C" void kernel_launch(void* const* d_in, const int* in_sizes, int n_in,
                              void* d_out, int out_size, void* d_ws, size_t ws_size,
                              hipStream_t stream) {
    const float* x  = (const float*)d_in[0];
    const int*   ei = (const int*)d_in[1];
    const float* w1 = (const float*)d_in[2];
    const float* b1 = (const float*)d_in[3];
    const float* w2 = (const float*)d_in[4];
    const float* b2 = (const float*)d_in[5];

    const int N = in_sizes[0] / 128;
    const int E = in_sizes[1] / 2;
    const int Mp = ((N + 127) / 128) * 128;
    const int NBK = (N + BNODES - 1) >> BSH;
    const int* srcIdx = ei;
    const int* dstIdx = ei + E;

    // workspace carve (256B aligned pieces)
    char* p = (char*)d_ws;
    int* rowst  = (int*)p;                 p = alignup(p + (size_t)N * 4, 256);
    int* rowend = (int*)p;                 p = alignup(p + (size_t)N * 4, 256);
    float* dis  = (float*)p;               p = alignup(p + (size_t)N * 4, 256);
    int* gCnt   = (int*)p;                 p = alignup(p + 128 * 4, 256);
    int* bucketPad = (int*)p;              p = alignup(p + 128 * 4, 256);
    int2* csr   = (int2*)p;                p = alignup(p + ((size_t)E + 8 * (size_t)N) * 8, 256);
    u16* Bp1    = (u16*)p;                 p = alignup(p + (size_t)128 * 512 * 2, 256);
    u16* Bp2    = (u16*)p;                 p = alignup(p + (size_t)128 * 128 * 2, 256);
    u16* G      = (u16*)p;                 p = alignup(p + (size_t)Mp * 512 * 2, 256);
    const size_t GS = (size_t)Mp * 128;
    // t2 region doubles as the partition stage buffer (dead until prop#1)
    size_t t2Bytes = GS * 2, stageBytes = (size_t)NBK * BCAP * 4;
    size_t u = t2Bytes > stageBytes ? t2Bytes : stageBytes;
    u16* t2     = (u16*)p;
    u32* stage  = (u32*)p;                 p = alignup(p + u, 256);
    u16* t1     = (u16*)p;                 p = alignup(p + GS * 2, 256);
    u16* h      = (u16*)p;                 p = alignup(p + GS * 2, 256);
    u16* Gc = G;
    u16* s1 = t2;
    u16* s2 = t1;

    hipMemsetAsync(gCnt, 0, 128 * sizeof(int), stream);

    // ---- CSR build (bucketed counting sort; single-XCD-owned csr writes)
    k_part<<<(E + 1023) / 1024, 256, 0, stream>>>(srcIdx, dstIdx, E, gCnt, stage);
    k_b1  <<<NBK, 256, 0, stream>>>(stage, gCnt, dis, bucketPad, N);
    k_b2  <<<NBK, 256, 0, stream>>>(stage, gCnt, bucketPad, dis, rowst, rowend, csr, N);
    k_packBoth<<<(10240 + 255) / 256, 256, 0, stream>>>(w1, w2, Bp1, Bp2);

    const int gb = Mp / 128;
    const int pwBlocks = ((N + 3) / 4) * 2;
    const int pqBlocks = (N * 32 + 255) / 256;

    // ---- layer 1: Gk = x @ W1_k (4 dense buffers), fused fp32->bf16
    k_gemm<1><<<gb, 256, 0, stream>>>(x, Bp1, G, GS, 4, N);
    // Horner: t2 = A*G3 + G2 ; t1 = A*t2 + G1 ; h = relu(A*t1 + G0 + b1)
    k_prop_w<<<pwBlocks, 256, 0, stream>>>(G + 3 * GS, G + 2 * GS, nullptr, 0,
                                           csr, rowst, rowend, t2, N);
    k_prop_w<<<pwBlocks, 256, 0, stream>>>(t2, G + 1 * GS, nullptr, 0,
                                           csr, rowst, rowend, t1, N);
    k_prop_w<<<pwBlocks, 256, 0, stream>>>(t1, G + 0 * GS, b1, 1,
                                           csr, rowst, rowend, h, N);

    // ---- layer 2: Gc = h @ [V0|V1|V2|V3] (dense 128 cols), 32-wide Horner
    k_gemm<0><<<gb, 256, 0, stream>>>(h, Bp2, Gc, GS, 1, N);
    k_prop_q<<<pqBlocks, 256, 0, stream>>>(Gc, 192, 0, Gc + 64, nullptr,
                                           csr, rowst, rowend, s1, nullptr, N);
    k_prop_q<<<pqBlocks, 256, 0, stream>>>(s1, 0, 2, Gc + 32, nullptr,
                                           csr, rowst, rowend, s2, nullptr, N);
    k_prop_q<<<pqBlocks, 256, 0, stream>>>(s2, 0, 2, Gc, b2,
                                           csr, rowst, rowend, nullptr, (float*)d_out, N);
}

// Round 8
// 336.663 us; speedup vs baseline: 1.3016x; 1.1476x over previous
//
#include <hip/hip_runtime.h>
#include <hip/hip_bf16.h>
#include <stdint.h>

typedef unsigned short u16;
typedef unsigned int u32;
typedef unsigned long long u64;
using f32x4  = __attribute__((ext_vector_type(4))) float;
using bf16x8 = __attribute__((ext_vector_type(8))) short;

__device__ __forceinline__ float b2f(u16 u) {
    return __uint_as_float((u32)u << 16);
}
__device__ __forceinline__ u16 f2b(float f) {
    __hip_bfloat16 h = __float2bfloat16(f);
    return *reinterpret_cast<u16*>(&h);
}
__device__ __forceinline__ short f2bs(float f) {
    return (short)f2b(f);
}
__device__ __forceinline__ int padd8(int d) { return (d + 7) & ~7; }

// ---------------------------------------------------------------------------
// Bucketed CSR build. Bucket = 512 consecutive dst nodes (dst>>9).
#define BSH 9
#define BNODES (1 << BSH)
#define BCAP 16384          // stage capacity per bucket (mean 8.2k)

// partition edges into buckets; stage entry = (src<<9) | (dst&511)
__global__ __launch_bounds__(256) void k_part(
        const int* __restrict__ src, const int* __restrict__ dst, int E,
        int* __restrict__ gCnt, u32* __restrict__ stage) {
    __shared__ int hist[128];
    __shared__ int runBase[128];
    const int tid = threadIdx.x;
    if (tid < 128) hist[tid] = 0;
    __syncthreads();
    const int base = blockIdx.x * 1024 + tid * 4;
    int s[4], d[4], bk[4], rk[4];
    bool ok[4];
    if (base + 3 < E) {
        int4 sv = *reinterpret_cast<const int4*>(src + base);
        int4 dv = *reinterpret_cast<const int4*>(dst + base);
        s[0]=sv.x; s[1]=sv.y; s[2]=sv.z; s[3]=sv.w;
        d[0]=dv.x; d[1]=dv.y; d[2]=dv.z; d[3]=dv.w;
        ok[0]=ok[1]=ok[2]=ok[3]=true;
    } else {
        #pragma unroll
        for (int j = 0; j < 4; ++j) {
            ok[j] = (base + j) < E;
            s[j] = ok[j] ? src[base + j] : 0;
            d[j] = ok[j] ? dst[base + j] : 0;
        }
    }
    #pragma unroll
    for (int j = 0; j < 4; ++j)
        if (ok[j]) { bk[j] = d[j] >> BSH; rk[j] = atomicAdd(&hist[bk[j]], 1); }
    __syncthreads();
    if (tid < 128) {
        int c = hist[tid];
        runBase[tid] = c ? atomicAdd(&gCnt[tid], c) : 0;
    }
    __syncthreads();
    #pragma unroll
    for (int j = 0; j < 4; ++j)
        if (ok[j])
            stage[(size_t)bk[j] * BCAP + runBase[bk[j]] + rk[j]] =
                ((u32)s[j] << BSH) | (u32)(d[j] & (BNODES - 1));
}

// per bucket: histogram -> dis (deg^-0.5) + padded-size total
__global__ __launch_bounds__(256) void k_b1(
        const u32* __restrict__ stage, const int* __restrict__ gCnt,
        float* __restrict__ dis, int* __restrict__ bucketPad, int N) {
    __shared__ int hist[BNODES];
    __shared__ int sW[4];
    const int b = blockIdx.x, tid = threadIdx.x;
    for (int i = tid; i < BNODES; i += 256) hist[i] = 0;
    __syncthreads();
    const int cnt = gCnt[b];
    const u32* st = stage + (size_t)b * BCAP;
    for (int e = tid; e < cnt; e += 256)
        atomicAdd(&hist[st[e] & (BNODES - 1)], 1);
    __syncthreads();
    const int nbase = b << BSH;
    int ps = 0;
    for (int i = tid; i < BNODES; i += 256) {
        int node = nbase + i;
        if (node < N) {
            int dg = hist[i];
            dis[node] = dg > 0 ? (1.0f / sqrtf((float)dg)) : 0.0f;
            ps += padd8(dg);
        }
    }
    #pragma unroll
    for (int off = 32; off; off >>= 1) ps += __shfl_down(ps, off, 64);
    int lane = tid & 63, wv = tid >> 6;
    if (lane == 0) sW[wv] = ps;
    __syncthreads();
    if (tid == 0) bucketPad[b] = sW[0] + sW[1] + sW[2] + sW[3];
}

// per bucket: re-histogram + scan -> rowst/rowend + pad + csr fill (LDS atomics)
// csr payload: (src<<8 byte-offset for 256B dense rows, weight)
__global__ __launch_bounds__(256) void k_b2(
        const u32* __restrict__ stage, const int* __restrict__ gCnt,
        const int* __restrict__ bucketPad, const float* __restrict__ dis,
        int* __restrict__ rowst, int* __restrict__ rowend,
        int2* __restrict__ csr, int N) {
    __shared__ int hist[BNODES];
    __shared__ int lofs[BNODES];
    __shared__ int cur[BNODES];
    __shared__ int sW[4];
    const int b = blockIdx.x, tid = threadIdx.x;
    for (int i = tid; i < BNODES; i += 256) hist[i] = 0;
    __syncthreads();
    const int cnt = gCnt[b];
    const u32* st = stage + (size_t)b * BCAP;
    for (int e = tid; e < cnt; e += 256)
        atomicAdd(&hist[st[e] & (BNODES - 1)], 1);
    __syncthreads();
    const int i0 = tid * 2, i1 = tid * 2 + 1;
    const int p0 = padd8(hist[i0]), p1 = padd8(hist[i1]);
    const int sps = p0 + p1;
    int x = sps;
    #pragma unroll
    for (int off = 1; off < 64; off <<= 1) {
        int y = __shfl_up(x, off, 64);
        if ((tid & 63) >= off) x += y;
    }
    int lane = tid & 63, wv = tid >> 6;
    if (lane == 63) sW[wv] = x;
    __syncthreads();
    if (tid == 0) {
        int run = 0;
        #pragma unroll
        for (int w = 0; w < 4; ++w) { int t = sW[w]; sW[w] = run; run += t; }
    }
    __syncthreads();
    const int excl = sW[wv] + (x - sps);
    lofs[i0] = excl;
    lofs[i1] = excl + p0;
    int boff = 0;
    for (int bb = 0; bb < b; ++bb) boff += bucketPad[bb];
    __syncthreads();
    const int nbase = b << BSH;
    for (int i = tid; i < BNODES; i += 256) {
        cur[i] = lofs[i];
        int node = nbase + i;
        if (node < N) {
            int dg = hist[i];
            int rsG = boff + lofs[i];
            rowst[node] = rsG;
            rowend[node] = rsG + padd8(dg);
            for (int e = dg; e < padd8(dg); ++e)
                csr[rsG + e] = make_int2(0, 0);
        }
    }
    __syncthreads();
    for (int e = tid; e < cnt; e += 256) {
        u32 sd = st[e];
        int ld = sd & (BNODES - 1);
        int s = (int)(sd >> BSH);
        int lpos = atomicAdd(&cur[ld], 1);
        float w = dis[s] * dis[nbase + ld];
        csr[boff + lpos] = make_int2(s << 8, __float_as_int(w));
    }
}

// ---------------------------------------------------------------------------
// pack both weight tensors into MFMA W-operand fragment order:
// frag f = nblock*4 + ks; lane l holds W[ks*32 + (l>>4)*8 + i][nblock*16 + (l&15)]
__global__ void k_packBoth(const float* __restrict__ w1, const float* __restrict__ w2,
                           u16* __restrict__ Bp1, u16* __restrict__ Bp2) {
    int t = blockIdx.x * blockDim.x + threadIdx.x;
    const float* W; u16* Bp; int log2cw; int tt;
    if (t < 8192)        { W = w1; Bp = Bp1; log2cw = 7; tt = t; }
    else if (t < 10240)  { W = w2; Bp = Bp2; log2cw = 5; tt = t - 8192; }
    else return;
    int lane = tt & 63;
    int f = tt >> 6;
    int ks = f & 3, nblock = f >> 2;
    int col = nblock * 16 + (lane & 15);
    int cw = 1 << log2cw;
    int kterm = col >> log2cw, c = col & (cw - 1);
    int kbase = ks * 32 + (lane >> 4) * 8;
    u16 out[8];
    #pragma unroll
    for (int i = 0; i < 8; ++i)
        out[i] = f2b(W[((size_t)kterm * 128 + (kbase + i)) * cw + c]);
    *reinterpret_cast<uint4*>(Bp + (size_t)tt * 8) = *reinterpret_cast<uint4*>(out);
}

// ---------------------------------------------------------------------------
// MFMA GEMM, operand-swapped: acc = mfma(W_frag [A-op], X_frag [B-op], acc)
// => D row = output feature (lh*4+reg), D col = node (li): lane packs 4
// consecutive features of one node into ONE 8B store.
// Column block cb = blockIdx.y (full grid occupancy). RG = row-groups/wave
// (wave covers RG*16 rows; block covers RG*64 rows).
template<int A_FP32, int RG>
__global__ __launch_bounds__(256) void k_gemm(
        const void* __restrict__ Av, const u16* __restrict__ Bp,
        u16* __restrict__ Out, size_t outStride, int Mvalid) {
    const int lane = threadIdx.x & 63;
    const int wv = threadIdx.x >> 6;
    const int cb = blockIdx.y;
    const int rowBase = blockIdx.x * (RG * 64) + wv * (RG * 16);
    const int li = lane & 15, lh = lane >> 4;

    bf16x8 a[RG][4];
    #pragma unroll
    for (int rg = 0; rg < RG; ++rg) {
        int r = rowBase + rg * 16 + li;
        bool ok = (r < Mvalid);
        #pragma unroll
        for (int ks = 0; ks < 4; ++ks) {
            int feat = ks * 32 + lh * 8;
            bf16x8 v = {0,0,0,0,0,0,0,0};
            if (ok) {
                if (A_FP32) {
                    const float* A = (const float*)Av;
                    const float* p = A + (size_t)r * 128 + feat;
                    float4 f0 = *reinterpret_cast<const float4*>(p);
                    float4 f1 = *reinterpret_cast<const float4*>(p + 4);
                    v[0] = f2bs(f0.x); v[1] = f2bs(f0.y);
                    v[2] = f2bs(f0.z); v[3] = f2bs(f0.w);
                    v[4] = f2bs(f1.x); v[5] = f2bs(f1.y);
                    v[6] = f2bs(f1.z); v[7] = f2bs(f1.w);
                } else {
                    const u16* A = (const u16*)Av;
                    v = *reinterpret_cast<const bf16x8*>(A + (size_t)r * 128 + feat);
                }
            }
            a[rg][ks] = v;
        }
    }

    f32x4 acc[RG][8];
    #pragma unroll
    for (int i = 0; i < RG; ++i)
        #pragma unroll
        for (int j = 0; j < 8; ++j)
            acc[i][j] = (f32x4){0.f, 0.f, 0.f, 0.f};
    #pragma unroll
    for (int ks = 0; ks < 4; ++ks) {
        #pragma unroll
        for (int nf = 0; nf < 8; ++nf) {
            const u16* pb = Bp + ((size_t)((cb * 8 + nf) * 4 + ks) * 64 + lane) * 8;
            bf16x8 wfr = *reinterpret_cast<const bf16x8*>(pb);
            #pragma unroll
            for (int rg = 0; rg < RG; ++rg)
                acc[rg][nf] = __builtin_amdgcn_mfma_f32_16x16x32_bf16(wfr, a[rg][ks], acc[rg][nf], 0, 0, 0);
        }
    }
    // D: row = feature-in-16 = lh*4+r, col = node-in-16 = li  [m89]
    u16* Ob = Out + (size_t)cb * outStride;
    #pragma unroll
    for (int rg = 0; rg < RG; ++rg) {
        int node = rowBase + rg * 16 + li;
        if (node < Mvalid) {
            #pragma unroll
            for (int nf = 0; nf < 8; ++nf) {
                u64 pk = (u64)f2b(acc[rg][nf][0])
                       | ((u64)f2b(acc[rg][nf][1]) << 16)
                       | ((u64)f2b(acc[rg][nf][2]) << 32)
                       | ((u64)f2b(acc[rg][nf][3]) << 48);
                *reinterpret_cast<u64*>(&Ob[(size_t)node * 128 + nf * 16 + lh * 4]) = pk;
            }
        }
    }
}

// ---------------------------------------------------------------------------
// 128-wide propagation (dense 256B rows, byte-offset csr, padded rows):
// wave per node, lane = 2 feats (u32 gather). out = A*X + Add (+bias)(relu).
__global__ __launch_bounds__(256) void k_prop_w(
        const u16* __restrict__ X,
        const u16* __restrict__ Add,
        const float* __restrict__ bias, int relu,
        const int2* __restrict__ csr, const int* __restrict__ rs,
        const int* __restrict__ re,
        u16* __restrict__ Out, int n) {
    int gw = (int)((blockIdx.x * (size_t)blockDim.x + threadIdx.x) >> 6);
    int lane = threadIdx.x & 63;
    if (gw >= n) return;
    const char* Xb = (const char*)X + lane * 4;
    int beg = rs[gw], end = re[gw];
    float ax = 0.f, ay = 0.f, bx = 0.f, by = 0.f;
    for (int e = beg; e < end; e += 8) {
        int2 c[8];
        #pragma unroll
        for (int j = 0; j < 8; ++j) c[j] = csr[e + j];
        u32 u[8];
        #pragma unroll
        for (int j = 0; j < 8; ++j)
            u[j] = *reinterpret_cast<const u32*>(Xb + (size_t)(u32)c[j].x);
        #pragma unroll
        for (int j = 0; j < 8; ++j) {
            float w = __int_as_float(c[j].y);
            if (j & 1) { bx += w * b2f(u[j] & 0xffff); by += w * b2f(u[j] >> 16); }
            else       { ax += w * b2f(u[j] & 0xffff); ay += w * b2f(u[j] >> 16); }
        }
    }
    ax += bx; ay += by;
    const int fo = lane * 2;
    if (Add) {
        u32 a = __builtin_nontemporal_load(
            reinterpret_cast<const u32*>(Add + (size_t)gw * 128 + fo));
        ax += b2f(a & 0xffff);
        ay += b2f(a >> 16);
    }
    if (bias) { ax += bias[fo]; ay += bias[fo + 1]; }
    if (relu) { ax = fmaxf(ax, 0.f); ay = fmaxf(ay, 0.f); }
    u32 o = (u32)f2b(ax) | ((u32)f2b(ay) << 16);
    __builtin_nontemporal_store(o, reinterpret_cast<u32*>(Out + (size_t)gw * 128 + fo));
}

// 32-wide propagation: 32 threads per node; X row byte-offset = csr>>rsh,
// slice base xoffB bytes. Add is a Gc slice (dense stride 128). Padded rows.
__global__ __launch_bounds__(256) void k_prop_q(
        const u16* __restrict__ X, int xoffB, int rsh,
        const u16* __restrict__ Add,
        const float* __restrict__ bias,
        const int2* __restrict__ csr, const int* __restrict__ rs,
        const int* __restrict__ re,
        u16* __restrict__ OutB, float* __restrict__ OutF, int n) {
    int t = blockIdx.x * blockDim.x + threadIdx.x;
    int node = t >> 5, j = t & 31;
    if (node >= n) return;
    const char* Xb = (const char*)X + xoffB + j * 2;
    float acc = 0.f, acc2 = 0.f;
    int beg = rs[node], end = re[node];
    for (int e = beg; e < end; e += 8) {
        int2 c[8];
        #pragma unroll
        for (int q = 0; q < 8; ++q) c[q] = csr[e + q];
        float v[8];
        #pragma unroll
        for (int q = 0; q < 8; ++q)
            v[q] = b2f(*reinterpret_cast<const u16*>(Xb + ((size_t)(u32)c[q].x >> rsh)));
        #pragma unroll
        for (int q = 0; q < 8; ++q) {
            if (q & 1) acc2 += __int_as_float(c[q].y) * v[q];
            else       acc  += __int_as_float(c[q].y) * v[q];
        }
    }
    acc += acc2;
    if (Add) acc += b2f(__builtin_nontemporal_load(Add + (size_t)node * 128 + j));
    if (bias) acc += bias[j];
    if (OutF) __builtin_nontemporal_store(acc, OutF + (size_t)node * 32 + j);
    else      __builtin_nontemporal_store(f2b(acc), OutB + (size_t)node * 32 + j);
}

// ---------------------------------------------------------------------------
static inline char* alignup(char* p, size_t a) {
    return (char*)(((uintptr_t)p + a - 1) & ~(uintptr_t)(a - 1));
}

extern "C" void kernel_launch(void* const* d_in, const int* in_sizes, int n_in,
                              void* d_out, int out_size, void* d_ws, size_t ws_size,
                              hipStream_t stream) {
    const float* x  = (const float*)d_in[0];
    const int*   ei = (const int*)d_in[1];
    const float* w1 = (const float*)d_in[2];
    const float* b1 = (const float*)d_in[3];
    const float* w2 = (const float*)d_in[4];
    const float* b2 = (const float*)d_in[5];

    const int N = in_sizes[0] / 128;
    const int E = in_sizes[1] / 2;
    const int Mp = ((N + 127) / 128) * 128;
    const int NBK = (N + BNODES - 1) >> BSH;
    const int* srcIdx = ei;
    const int* dstIdx = ei + E;

    // workspace carve (256B aligned pieces)
    char* p = (char*)d_ws;
    int* rowst  = (int*)p;                 p = alignup(p + (size_t)N * 4, 256);
    int* rowend = (int*)p;                 p = alignup(p + (size_t)N * 4, 256);
    float* dis  = (float*)p;               p = alignup(p + (size_t)N * 4, 256);
    int* gCnt   = (int*)p;                 p = alignup(p + 128 * 4, 256);
    int* bucketPad = (int*)p;              p = alignup(p + 128 * 4, 256);
    int2* csr   = (int2*)p;                p = alignup(p + ((size_t)E + 8 * (size_t)N) * 8, 256);
    u16* Bp1    = (u16*)p;                 p = alignup(p + (size_t)128 * 512 * 2, 256);
    u16* Bp2    = (u16*)p;                 p = alignup(p + (size_t)128 * 128 * 2, 256);
    u16* G      = (u16*)p;                 p = alignup(p + (size_t)Mp * 512 * 2, 256);
    const size_t GS = (size_t)Mp * 128;
    // t2 region doubles as the partition stage buffer (dead until prop#1)
    size_t t2Bytes = GS * 2, stageBytes = (size_t)NBK * BCAP * 4;
    size_t u = t2Bytes > stageBytes ? t2Bytes : stageBytes;
    u16* t2     = (u16*)p;
    u32* stage  = (u32*)p;                 p = alignup(p + u, 256);
    u16* t1     = (u16*)p;                 p = alignup(p + GS * 2, 256);
    u16* h      = (u16*)p;                 p = alignup(p + GS * 2, 256);
    u16* Gc = G;
    u16* s1 = t2;
    u16* s2 = t1;

    hipMemsetAsync(gCnt, 0, 128 * sizeof(int), stream);

    // ---- CSR build (bucketed counting sort; single-XCD-owned csr writes)
    k_part<<<(E + 1023) / 1024, 256, 0, stream>>>(srcIdx, dstIdx, E, gCnt, stage);
    k_b1  <<<NBK, 256, 0, stream>>>(stage, gCnt, dis, bucketPad, N);
    k_b2  <<<NBK, 256, 0, stream>>>(stage, gCnt, bucketPad, dis, rowst, rowend, csr, N);
    k_packBoth<<<(10240 + 255) / 256, 256, 0, stream>>>(w1, w2, Bp1, Bp2);

    const int pb128 = (N * 64 + 255) / 256;
    const int pqBlocks = (N * 32 + 255) / 256;

    // ---- layer 1: Gk = x @ W1_k (4 dense buffers); cb in blockIdx.y
    k_gemm<1, 2><<<dim3(Mp / 128, 4), 256, 0, stream>>>(x, Bp1, G, GS, N);
    // Horner: t2 = A*G3 + G2 ; t1 = A*t2 + G1 ; h = relu(A*t1 + G0 + b1)
    k_prop_w<<<pb128, 256, 0, stream>>>(G + 3 * GS, G + 2 * GS, nullptr, 0,
                                        csr, rowst, rowend, t2, N);
    k_prop_w<<<pb128, 256, 0, stream>>>(t2, G + 1 * GS, nullptr, 0,
                                        csr, rowst, rowend, t1, N);
    k_prop_w<<<pb128, 256, 0, stream>>>(t1, G + 0 * GS, b1, 1,
                                        csr, rowst, rowend, h, N);

    // ---- layer 2: Gc = h @ [V0|V1|V2|V3] (dense 128 cols), 64-row blocks
    k_gemm<0, 1><<<dim3(Mp / 64, 1), 256, 0, stream>>>(h, Bp2, Gc, GS, N);
    k_prop_q<<<pqBlocks, 256, 0, stream>>>(Gc, 192, 0, Gc + 64, nullptr,
                                           csr, rowst, rowend, s1, nullptr, N);
    k_prop_q<<<pqBlocks, 256, 0, stream>>>(s1, 0, 2, Gc + 32, nullptr,
                                           csr, rowst, rowend, s2, nullptr, N);
    k_prop_q<<<pqBlocks, 256, 0, stream>>>(s2, 0, 2, Gc, b2,
                                           csr, rowst, rowend, nullptr, (float*)d_out, N);
}